// Round 1
// baseline (1629.718 us; speedup 1.0000x reference)
//
#include <hip/hip_runtime.h>

#define EPS_BN 1e-4f
constexpr int BLK = 256;

// ---------------- conv_in: [N,3] x [27,3,32] -> [N,32] ----------------
__global__ __launch_bounds__(BLK) void conv_in_k(
    const float* __restrict__ feat, const int* __restrict__ nbr,
    const float* __restrict__ W, float* __restrict__ out, int n) {
  int i = blockIdx.x * BLK + threadIdx.x;
  if (i >= n) return;
  float acc[32];
#pragma unroll
  for (int c = 0; c < 32; ++c) acc[c] = 0.f;
  const int* nr = nbr + i * 27;
#pragma unroll 1
  for (int k = 0; k < 27; ++k) {
    int j = nr[k];
    if (j < 0) continue;
    float x0 = feat[j * 3 + 0], x1 = feat[j * 3 + 1], x2 = feat[j * 3 + 2];
    const float* w0 = W + k * 3 * 32;
#pragma unroll
    for (int co = 0; co < 8; ++co) {
      float4 a = *reinterpret_cast<const float4*>(w0 + co * 4);
      float4 b = *reinterpret_cast<const float4*>(w0 + 32 + co * 4);
      float4 cc = *reinterpret_cast<const float4*>(w0 + 64 + co * 4);
      acc[4*co+0] = fmaf(x0, a.x, fmaf(x1, b.x, fmaf(x2, cc.x, acc[4*co+0])));
      acc[4*co+1] = fmaf(x0, a.y, fmaf(x1, b.y, fmaf(x2, cc.y, acc[4*co+1])));
      acc[4*co+2] = fmaf(x0, a.z, fmaf(x1, b.z, fmaf(x2, cc.z, acc[4*co+2])));
      acc[4*co+3] = fmaf(x0, a.w, fmaf(x1, b.w, fmaf(x2, cc.w, acc[4*co+3])));
    }
  }
  float* o = out + i * 32;
#pragma unroll
  for (int co = 0; co < 8; ++co)
    *reinterpret_cast<float4*>(o + co * 4) = make_float4(acc[4*co], acc[4*co+1], acc[4*co+2], acc[4*co+3]);
}

// ------------- generic subm conv with fused BN+ReLU on input -------------
// st = [scale[CI], shift[CI]]; W = [27, CI, CO]
template <int CI, int CO>
__global__ __launch_bounds__(BLK) void bnconv_k(
    const float* __restrict__ fin, const int* __restrict__ nbr,
    const float* __restrict__ st, const float* __restrict__ W,
    float* __restrict__ out, int n) {
  int i = blockIdx.x * BLK + threadIdx.x;
  if (i >= n) return;
  float acc[CO];
#pragma unroll
  for (int c = 0; c < CO; ++c) acc[c] = 0.f;
  const int* nr = nbr + i * 27;
#pragma unroll 1
  for (int k = 0; k < 27; ++k) {
    int j = nr[k];
    if (j < 0) continue;
    const float* fj = fin + (size_t)j * CI;
    const float* wk = W + k * CI * CO;
#pragma unroll 1
    for (int c4 = 0; c4 < CI; c4 += 4) {
      float4 xv = *reinterpret_cast<const float4*>(fj + c4);
      float xs[4] = {xv.x, xv.y, xv.z, xv.w};
#pragma unroll
      for (int q = 0; q < 4; ++q) {
        int c = c4 + q;
        float x = fmaf(xs[q], st[c], st[CI + c]);
        x = x > 0.f ? x : 0.f;
        const float* wr = wk + c * CO;
#pragma unroll
        for (int co = 0; co < CO / 4; ++co) {
          float4 wv = *reinterpret_cast<const float4*>(wr + co * 4);
          acc[4*co+0] = fmaf(x, wv.x, acc[4*co+0]);
          acc[4*co+1] = fmaf(x, wv.y, acc[4*co+1]);
          acc[4*co+2] = fmaf(x, wv.z, acc[4*co+2]);
          acc[4*co+3] = fmaf(x, wv.w, acc[4*co+3]);
        }
      }
    }
  }
  float* o = out + (size_t)i * CO;
#pragma unroll
  for (int co = 0; co < CO / 4; ++co)
    *reinterpret_cast<float4*>(o + co * 4) = make_float4(acc[4*co], acc[4*co+1], acc[4*co+2], acc[4*co+3]);
}

// ------- concat conv: inputs fa (32ch, sta) and fb (32ch, stb), CO=32 -------
__global__ __launch_bounds__(BLK) void conv_cat_k(
    const float* __restrict__ fa, const float* __restrict__ fb,
    const int* __restrict__ nbr, const float* __restrict__ sta,
    const float* __restrict__ stb, const float* __restrict__ W,
    float* __restrict__ out, int n) {
  int i = blockIdx.x * BLK + threadIdx.x;
  if (i >= n) return;
  float acc[32];
#pragma unroll
  for (int c = 0; c < 32; ++c) acc[c] = 0.f;
  const int* nr = nbr + i * 27;
#pragma unroll 1
  for (int k = 0; k < 27; ++k) {
    int j = nr[k];
    if (j < 0) continue;
    const float* wk = W + k * 64 * 32;
#pragma unroll 1
    for (int half = 0; half < 2; ++half) {
      const float* fj = (half == 0 ? fa : fb) + (size_t)j * 32;
      const float* sth = half == 0 ? sta : stb;
      const float* wkh = wk + half * 32 * 32;
#pragma unroll 1
      for (int c4 = 0; c4 < 32; c4 += 4) {
        float4 xv = *reinterpret_cast<const float4*>(fj + c4);
        float xs[4] = {xv.x, xv.y, xv.z, xv.w};
#pragma unroll
        for (int q = 0; q < 4; ++q) {
          int c = c4 + q;
          float x = fmaf(xs[q], sth[c], sth[32 + c]);
          x = x > 0.f ? x : 0.f;
          const float* wr = wkh + c * 32;
#pragma unroll
          for (int co = 0; co < 8; ++co) {
            float4 wv = *reinterpret_cast<const float4*>(wr + co * 4);
            acc[4*co+0] = fmaf(x, wv.x, acc[4*co+0]);
            acc[4*co+1] = fmaf(x, wv.y, acc[4*co+1]);
            acc[4*co+2] = fmaf(x, wv.z, acc[4*co+2]);
            acc[4*co+3] = fmaf(x, wv.w, acc[4*co+3]);
          }
        }
      }
    }
  }
  float* o = out + (size_t)i * 32;
#pragma unroll
  for (int co = 0; co < 8; ++co)
    *reinterpret_cast<float4*>(o + co * 4) = make_float4(acc[4*co], acc[4*co+1], acc[4*co+2], acc[4*co+3]);
}

// ---------------- per-channel sum / sumsq ----------------
template <int C>
__global__ __launch_bounds__(BLK) void stats_k(
    const float* __restrict__ f, int n, float* __restrict__ sums) {
  constexpr int G = BLK / C;
  int c = threadIdx.x % C;
  int g = threadIdx.x / C;
  float s = 0.f, ss = 0.f;
  for (int r = blockIdx.x * G + g; r < n; r += gridDim.x * G) {
    float x = f[(size_t)r * C + c];
    s += x;
    ss += x * x;
  }
  __shared__ float ls[BLK], lss[BLK];
  ls[threadIdx.x] = s;
  lss[threadIdx.x] = ss;
  __syncthreads();
  if (threadIdx.x < C) {
    float ts = 0.f, tss = 0.f;
#pragma unroll
    for (int q = 0; q < G; ++q) { ts += ls[q * C + c]; tss += lss[q * C + c]; }
    atomicAdd(&sums[c], ts);
    atomicAdd(&sums[C + c], tss);
  }
}

// mu/var -> scale/shift  (y = x*scale + shift, then relu in consumer)
__global__ void finalize_k(const float* __restrict__ sums,
                           const float* __restrict__ gamma,
                           const float* __restrict__ beta, float inv_n,
                           float* __restrict__ st, int C) {
  int c = threadIdx.x;
  if (c >= C) return;
  float mu = sums[c] * inv_n;
  float var = sums[C + c] * inv_n - mu * mu;
  float sc = gamma[c] / sqrtf(var + EPS_BN);
  st[c] = sc;
  st[C + c] = beta[c] - mu * sc;
}

// ---------------- down: scatter-add bn(f2) @ W[off] into coarse ----------------
__global__ __launch_bounds__(BLK) void down_k(
    const float* __restrict__ fin, const float* __restrict__ st,
    const int* __restrict__ parent, const int* __restrict__ offid,
    const float* __restrict__ W, float* __restrict__ gout, int n) {
  int i = blockIdx.x * BLK + threadIdx.x;
  if (i >= n) return;
  float acc[64];
#pragma unroll
  for (int c = 0; c < 64; ++c) acc[c] = 0.f;
  int o = offid[i], p = parent[i];
  const float* wk = W + o * 32 * 64;
  const float* fj = fin + (size_t)i * 32;
#pragma unroll 1
  for (int c4 = 0; c4 < 32; c4 += 4) {
    float4 xv = *reinterpret_cast<const float4*>(fj + c4);
    float xs[4] = {xv.x, xv.y, xv.z, xv.w};
#pragma unroll
    for (int q = 0; q < 4; ++q) {
      int c = c4 + q;
      float x = fmaf(xs[q], st[c], st[32 + c]);
      x = x > 0.f ? x : 0.f;
      const float* wr = wk + c * 64;
#pragma unroll
      for (int co = 0; co < 16; ++co) {
        float4 wv = *reinterpret_cast<const float4*>(wr + co * 4);
        acc[4*co+0] = fmaf(x, wv.x, acc[4*co+0]);
        acc[4*co+1] = fmaf(x, wv.y, acc[4*co+1]);
        acc[4*co+2] = fmaf(x, wv.z, acc[4*co+2]);
        acc[4*co+3] = fmaf(x, wv.w, acc[4*co+3]);
      }
    }
  }
  float* gp = gout + (size_t)p * 64;
#pragma unroll
  for (int co = 0; co < 64; ++co) atomicAdd(&gp[co], acc[co]);
}

// ---------------- up: gather bn(g2c[parent]) @ Wup[off] -> [N,32] ----------------
__global__ __launch_bounds__(BLK) void up_k(
    const float* __restrict__ gin, const float* __restrict__ st,
    const int* __restrict__ parent, const int* __restrict__ offid,
    const float* __restrict__ W, float* __restrict__ out, int n) {
  int i = blockIdx.x * BLK + threadIdx.x;
  if (i >= n) return;
  float acc[32];
#pragma unroll
  for (int c = 0; c < 32; ++c) acc[c] = 0.f;
  int o = offid[i], p = parent[i];
  const float* wk = W + o * 64 * 32;
  const float* fj = gin + (size_t)p * 64;
#pragma unroll 1
  for (int c4 = 0; c4 < 64; c4 += 4) {
    float4 xv = *reinterpret_cast<const float4*>(fj + c4);
    float xs[4] = {xv.x, xv.y, xv.z, xv.w};
#pragma unroll
    for (int q = 0; q < 4; ++q) {
      int c = c4 + q;
      float x = fmaf(xs[q], st[c], st[64 + c]);
      x = x > 0.f ? x : 0.f;
      const float* wr = wk + c * 32;
#pragma unroll
      for (int co = 0; co < 8; ++co) {
        float4 wv = *reinterpret_cast<const float4*>(wr + co * 4);
        acc[4*co+0] = fmaf(x, wv.x, acc[4*co+0]);
        acc[4*co+1] = fmaf(x, wv.y, acc[4*co+1]);
        acc[4*co+2] = fmaf(x, wv.z, acc[4*co+2]);
        acc[4*co+3] = fmaf(x, wv.w, acc[4*co+3]);
      }
    }
  }
  float* o2 = out + (size_t)i * 32;
#pragma unroll
  for (int co = 0; co < 8; ++co)
    *reinterpret_cast<float4*>(o2 + co * 4) = make_float4(acc[4*co], acc[4*co+1], acc[4*co+2], acc[4*co+3]);
}

// ---------------- head: bn(f3) -> @ w_lin + b_lin -> [N,50] ----------------
__global__ __launch_bounds__(BLK) void head_k(
    const float* __restrict__ fin, const float* __restrict__ st,
    const float* __restrict__ Wl, const float* __restrict__ bl,
    float* __restrict__ out, int n) {
  int i = blockIdx.x * BLK + threadIdx.x;
  if (i >= n) return;
  float acc[50];
#pragma unroll
  for (int c = 0; c < 50; ++c) acc[c] = bl[c];
  const float* fj = fin + (size_t)i * 32;
#pragma unroll 1
  for (int c = 0; c < 32; ++c) {
    float x = fmaf(fj[c], st[c], st[32 + c]);
    x = x > 0.f ? x : 0.f;
    const float* wr = Wl + c * 50;
#pragma unroll
    for (int co = 0; co < 50; ++co) acc[co] = fmaf(x, wr[co], acc[co]);
  }
  float* o = out + (size_t)i * 50;
#pragma unroll
  for (int co = 0; co < 50; ++co) o[co] = acc[co];
}

extern "C" void kernel_launch(void* const* d_in, const int* in_sizes, int n_in,
                              void* d_out, int out_size, void* d_ws, size_t ws_size,
                              hipStream_t stream) {
  const float* feat   = (const float*)d_in[1];
  const int*   nbrF   = (const int*)d_in[2];
  const int*   nbrC   = (const int*)d_in[3];
  const int*   parent = (const int*)d_in[4];
  const int*   offid  = (const int*)d_in[5];
  const float* w_in   = (const float*)d_in[7];
  const float* w_b1   = (const float*)d_in[8];
  const float* w_down = (const float*)d_in[9];
  const float* w_b2   = (const float*)d_in[10];
  const float* w_up   = (const float*)d_in[11];
  const float* w_b3   = (const float*)d_in[12];
  const float* g1 = (const float*)d_in[13], *b1 = (const float*)d_in[14];
  const float* gd = (const float*)d_in[15], *bd = (const float*)d_in[16];
  const float* g2 = (const float*)d_in[17], *b2 = (const float*)d_in[18];
  const float* gu = (const float*)d_in[19], *bu = (const float*)d_in[20];
  const float* g3 = (const float*)d_in[21], *b3 = (const float*)d_in[22];
  const float* go = (const float*)d_in[23], *bo = (const float*)d_in[24];
  const float* w_lin = (const float*)d_in[25];
  const float* b_lin = (const float*)d_in[26];
  float* out = (float*)d_out;

  int N  = in_sizes[4];        // |parent|
  int NC = in_sizes[3] / 27;   // |nbr_coarse| / 27

  size_t szF = (size_t)N * 32;
  size_t szG = (size_t)NC * 64;
  size_t szC = szG > szF ? szG : szF;

  float* ws   = (float*)d_ws;
  float* f1   = ws;             // [N,32]; later reused as f3
  float* f2   = f1 + szF;       // [N,32] (skip)
  float* gC   = f2 + szF;       // [NC,64] coarse; later reused as u [N,32]
  float* g2c  = gC + szC;       // [NC,64]
  float* stats = g2c + szG;
  float* sums1 = stats;         // 64
  float* sumsD = sums1 + 64;    // 64
  float* sums2 = sumsD + 64;    // 128
  float* sumsU = sums2 + 128;   // 128
  float* sums4 = sumsU + 128;   // 64
  float* sums5 = sums4 + 64;    // 64
  float* st1   = sums5 + 64;    // 64
  float* stD   = st1 + 64;      // 64
  float* st3a  = stD + 64;      // 64
  float* st2   = st3a + 64;     // 128
  float* stU   = st2 + 128;     // 128
  float* st3b  = stU + 128;     // 64
  float* stO   = st3b + 64;     // 64

  hipMemsetAsync(stats, 0, 512 * sizeof(float), stream);
  hipMemsetAsync(gC, 0, szG * sizeof(float), stream);

  int gridN = (N + BLK - 1) / BLK;
  int gridC = (NC + BLK - 1) / BLK;
  int sgrid = 304;
  float invN = 1.f / (float)N, invC = 1.f / (float)NC;

  conv_in_k<<<gridN, BLK, 0, stream>>>(feat, nbrF, w_in, f1, N);
  stats_k<32><<<sgrid, BLK, 0, stream>>>(f1, N, sums1);
  finalize_k<<<1, 64, 0, stream>>>(sums1, g1, b1, invN, st1, 32);
  bnconv_k<32, 32><<<gridN, BLK, 0, stream>>>(f1, nbrF, st1, w_b1, f2, N);
  stats_k<32><<<sgrid, BLK, 0, stream>>>(f2, N, sumsD);
  finalize_k<<<1, 64, 0, stream>>>(sumsD, gd, bd, invN, stD, 32);
  finalize_k<<<1, 64, 0, stream>>>(sumsD, g3, b3, invN, st3a, 32);  // BN3 first half: same stats
  down_k<<<gridN, BLK, 0, stream>>>(f2, stD, parent, offid, w_down, gC, N);
  stats_k<64><<<sgrid, BLK, 0, stream>>>(gC, NC, sums2);
  finalize_k<<<1, 64, 0, stream>>>(sums2, g2, b2, invC, st2, 64);
  bnconv_k<64, 64><<<gridC, BLK, 0, stream>>>(gC, nbrC, st2, w_b2, g2c, NC);
  stats_k<64><<<sgrid, BLK, 0, stream>>>(g2c, NC, sumsU);
  finalize_k<<<1, 64, 0, stream>>>(sumsU, gu, bu, invC, stU, 64);
  up_k<<<gridN, BLK, 0, stream>>>(g2c, stU, parent, offid, w_up, gC, N);  // gC now = u [N,32]
  stats_k<32><<<sgrid, BLK, 0, stream>>>(gC, N, sums4);
  finalize_k<<<1, 64, 0, stream>>>(sums4, g3 + 32, b3 + 32, invN, st3b, 32);
  conv_cat_k<<<gridN, BLK, 0, stream>>>(f2, gC, nbrF, st3a, st3b, w_b3, f1, N);  // f3 -> f1 slot
  stats_k<32><<<sgrid, BLK, 0, stream>>>(f1, N, sums5);
  finalize_k<<<1, 64, 0, stream>>>(sums5, go, bo, invN, stO, 32);
  head_k<<<gridN, BLK, 0, stream>>>(f1, stO, w_lin, b_lin, out, N);
}